// Round 4
// baseline (196.973 us; speedup 1.0000x reference)
//
#include <hip/hip_runtime.h>

// Problem constants
#define NXC 128
#define NYC 128
#define NZC 4
#define BC  8
#define TC  10

#define TSTRIDE 65536            // NZ*NX*NY
#define NTOT    5242880          // B*T*NZ*NX*NY
#define NHALF   2621440          // NTOT/2

typedef float vf2 __attribute__((ext_vector_type(2)));

// 2 elements per thread via float2:
//  - r3 (scalar, 12 VGPR, occ 62%) proved occupancy alone adds only ~4%:
//    the system is bandwidth-saturated (~2.9 TB/s) for this pattern.
//  - scalar also RAISED FETCH_SIZE 74.4->82.8 MB (more concurrent lines ->
//    more LLC conflict evictions). float2 halves vmem instruction count and
//    doubles burst length (512B/wave/instr) while staying <=48 VGPRs ->
//    still 8 waves/EU natural occupancy. Goal: r0's FETCH + r3's occupancy.
//  - r2 lesson: never force the register budget (spill catastrophe).
__global__ __launch_bounds__(256) void blackoil_kernel(
    const float* __restrict__ pressure,
    const float* __restrict__ perm,
    const float* __restrict__ Q,
    const float* __restrict__ Qw,
    const float* __restrict__ Time_,
    const float* __restrict__ Phi,
    const float* __restrict__ Swini,
    const float* __restrict__ wsat,
    float* __restrict__ out)
{
    const int tid  = blockIdx.x * blockDim.x + threadIdx.x;  // 0..NHALF-1 exact
    const int base = tid << 1;                               // even element index

    const float sini = Swini[0];

    const int y = base & (NYC - 1);          // even, 0..126
    const int x = (base >> 7) & (NXC - 1);
    const int t = (base >> 16) % TC;

    // replicate-pad stencil offsets (match jnp.pad mode='edge')
    const int xm  = (x > 0)       ? -NYC : 0;
    const int xp  = (x < NXC - 1) ?  NYC : 0;
    const int ylo = (y > 0)       ? -1   : 0;   // element y-1 (edge: clamp)
    const int yro = (y < NYC - 2) ?  2   : 1;   // element y+2 (edge: y+1=127)

    // pressure 5-point stencil for the pair (y, y+1)
    const vf2  pc   = *(const vf2*)(pressure + base);
    const vf2  pxm  = *(const vf2*)(pressure + base + xm);
    const vf2  pxp  = *(const vf2*)(pressure + base + xp);
    const float pyl = pressure[base + ylo];
    const float pyr = pressure[base + yro];

    // perm at t=0 slice (mobility-derivative fields use channel 0 only)
    const int i0 = base - t * TSTRIDE;
    const vf2  k0c  = *(const vf2*)(perm + i0);
    const vf2  k0xm = *(const vf2*)(perm + i0 + xm);
    const vf2  k0xp = *(const vf2*)(perm + i0 + xp);
    const float k0yl = perm[i0 + ylo];
    const float k0yr = perm[i0 + yro];

    const vf2 kc = *(const vf2*)(perm + base);
    const vf2 sa = *(const vf2*)(wsat + base);
    // prior saturation: shifted wsat, or sini at t=0 (safe unconditional load)
    const vf2 prl = *(const vf2*)(wsat + base - ((t > 0) ? TSTRIDE : 0));

    // nontemporal: pure-streaming arrays stay OUT of L2 (r1 A/B: removing nt
    // left FETCH_SIZE identical but regressed via L2 pollution).
    const vf2 q  = __builtin_nontemporal_load((const vf2*)(Q     + base));
    const vf2 qw = __builtin_nontemporal_load((const vf2*)(Qw    + base));
    const vf2 tm = __builtin_nontemporal_load((const vf2*)(Time_ + base));
    const vf2 ph = __builtin_nontemporal_load((const vf2*)(Phi   + base));

    vf2 pr = prl;
    if (t == 0) { pr = (vf2){sini, sini}; }

    // mobility constants from siniuse
    const float S0 = (sini - 0.1f) * 1.25f;      // /(1-SWI-SWR)=0.8
    const float cw = S0 * S0;
    const float ct = cw + (1.0f - S0) * (1.0f - S0) * (1.0f / 2.75f);
    const float scale = 7.8125e-8f;              // dxf * 1e-5 = 1e-5/128
    const float DK = 32000.0f;                   // 500 (perm rescale) * 64 (0.5/h)

    // per-element stencil values for j=0 (y) and j=1 (y+1)
    const float ucA [2] = { pc.x,  pc.y  };
    const float uxmA[2] = { pxm.x, pxm.y };
    const float uxpA[2] = { pxp.x, pxp.y };
    const float uymA[2] = { pyl,   pc.x  };
    const float uypA[2] = { pc.y,  pyr   };

    const float k0mA[2] = { k0xm.x, k0xm.y };
    const float k0pA[2] = { k0xp.x, k0xp.y };
    const float kymA[2] = { k0yl,   k0c.x  };
    const float kypA[2] = { k0c.y,  k0yr   };

    const float kcA [2] = { kc.x, kc.y };
    const float saA [2] = { sa.x, sa.y };
    const float prA [2] = { pr.x, pr.y };
    const float qA  [2] = { q.x,  q.y  };
    const float qwA [2] = { qw.x, qw.y };
    const float tmA [2] = { tm.x, tm.y };
    const float phA [2] = { ph.x, ph.y };

    float pl[2], sl[2];
#pragma unroll
    for (int j = 0; j < 2; ++j) {
        const float uc   = ucA[j]  * 1000.0f;
        const float uxm2 = uxmA[j] * 1000.0f;
        const float uxp2 = uxpA[j] * 1000.0f;
        const float uym2 = uymA[j] * 1000.0f;
        const float uyp2 = uypA[j] * 1000.0f;

        const float dudx   = (uxp2 - uxm2) * 64.0f;
        const float dudy   = (uyp2 - uym2) * 64.0f;
        const float dduddx = (uxp2 - 2.0f * uc + uxm2) * 16384.0f;
        const float dduddy = (uyp2 - 2.0f * uc + uym2) * 16384.0f;

        const float dpx = (k0pA[j] - k0mA[j]) * DK;
        const float dpy = (kypA[j] - kymA[j]) * DK;
        const float g1  = dpx * dudx + dpy * dudy;
        const float lap = dduddx + dduddy;

        const float a   = 500.0f * kcA[j];
        const float dsw = fmaxf(saA[j] - prA[j], 0.001f);
        const float S   = (prA[j] - 0.1f) * 1.25f;
        const float Mw  = S * S;
        const float Mo  = (1.0f - S) * (1.0f - S) * (1.0f / 2.75f);
        const float a1  = (Mw + Mo) * a;
        const float a1w = Mw * a;

        pl[j] = scale * (qA[j] * 5000.0f + ct * g1 + a1 * lap);
        const float flux = cw * g1 + a1w * lap;
        sl[j] = scale * (phA[j] * (dsw / (tmA[j] * 6000.0f)) - (flux + qwA[j] * 5000.0f));
    }

    const vf2 po = { pl[0], pl[1] };
    const vf2 so = { sl[0], sl[1] };
    __builtin_nontemporal_store(po, (vf2*)(out + base));
    __builtin_nontemporal_store(so, (vf2*)(out + base + NTOT));
}

extern "C" void kernel_launch(void* const* d_in, const int* in_sizes, int n_in,
                              void* d_out, int out_size, void* d_ws, size_t ws_size,
                              hipStream_t stream) {
    const float* pressure = (const float*)d_in[0];
    const float* perm     = (const float*)d_in[1];
    const float* Q        = (const float*)d_in[2];
    const float* Qw       = (const float*)d_in[3];
    const float* Time_    = (const float*)d_in[4];
    // d_in[5] = Pini (unused by the reference)
    const float* Phi      = (const float*)d_in[6];
    const float* Swini    = (const float*)d_in[7];
    const float* wsat     = (const float*)d_in[8];
    float* out = (float*)d_out;

    const int threads = 256;
    const int blocks  = NHALF / threads;     // 10240
    blackoil_kernel<<<blocks, threads, 0, stream>>>(
        pressure, perm, Q, Qw, Time_, Phi, Swini, wsat, out);
}

// Round 5
// 196.043 us; speedup vs baseline: 1.0047x; 1.0047x over previous
//
#include <hip/hip_runtime.h>

// Problem constants
#define NXC 128
#define NYC 128
#define NZC 4
#define BC  8
#define TC  10

#define TSTRIDE 65536            // NZ*NX*NY
#define NTOT    5242880          // B*T*NZ*NX*NY
#define NBLOCKS 20480            // NTOT/256
#define CPX     2560             // NBLOCKS/8 XCDs

// r3 scalar structure (best: 43.7us, 12 VGPR, occ 62%) + two fabric/latency
// levers that rounds 0-4 never tested:
//  1. nt (HBM-latency) loads issued FIRST: in r3 they were last of 16 loads;
//     with 12 VGPRs the compiler drains fast LLC loads before issuing slow
//     ones -> ~900cy exposed latency. First = overlapped under LLC loads.
//  2. XCD-aware block swizzle (bijective, 20480%8==0): consecutive work
//     chunks per XCD -> x-halo rows and cross-t wsat slices become same-XCD
//     L2 hits instead of second trips over the LLC fabric (~5.3 TB/s est.
//     fabric load at r3 vs 2.9 TB/s HBM -- fabric is the suspected binder).
// Lessons kept: nt on streaming arrays (r1), no forced launch bounds (r2),
// scalar 1-elem/thread (r3 beat r0's 2-quad and r4's float2).
__global__ __launch_bounds__(256) void blackoil_kernel(
    const float* __restrict__ pressure,
    const float* __restrict__ perm,
    const float* __restrict__ Q,
    const float* __restrict__ Qw,
    const float* __restrict__ Time_,
    const float* __restrict__ Phi,
    const float* __restrict__ Swini,
    const float* __restrict__ wsat,
    float* __restrict__ out)
{
    // XCD swizzle: hardware round-robins blockIdx across 8 XCDs; remap so
    // each XCD gets a contiguous gid range (work w = (b%8)*CPX + b/8).
    const int bid = blockIdx.x;
    const int wid = (bid & 7) * CPX + (bid >> 3);
    const int gid = (wid << 8) + threadIdx.x;    // 0..NTOT-1 exact

    // ---- slow (HBM) streaming loads first: overlap their latency under
    // everything else. nt keeps them out of L2 (r1 A/B evidence).
    const float q  = __builtin_nontemporal_load(Q     + gid);
    const float qw = __builtin_nontemporal_load(Qw    + gid);
    const float tm = __builtin_nontemporal_load(Time_ + gid);
    const float ph = __builtin_nontemporal_load(Phi   + gid);

    const float sini = Swini[0];

    const int y = gid & (NYC - 1);
    const int x = (gid >> 7) & (NXC - 1);
    const int t = (gid >> 16) % TC;

    // replicate-pad stencil offsets (match jnp.pad mode='edge')
    const int xm = (x > 0)       ? -NYC : 0;
    const int xp = (x < NXC - 1) ?  NYC : 0;
    const int ym = (y > 0)       ? -1   : 0;
    const int yp = (y < NYC - 1) ?  1   : 0;

    // pressure 5-point stencil (coalesced dword loads; halos now same-XCD L2)
    const float pc  = pressure[gid];
    const float pxm = pressure[gid + xm];
    const float pxp = pressure[gid + xp];
    const float pym = pressure[gid + ym];
    const float pyp = pressure[gid + yp];

    // perm at t=0 slice of the same batch (mobility fields use channel 0,
    // broadcast over T; the 2.1 MB slice stays hot in each XCD's 4 MB L2)
    const int i0 = gid - t * TSTRIDE;
    const float k0xm = perm[i0 + xm];
    const float k0xp = perm[i0 + xp];
    const float k0ym = perm[i0 + ym];
    const float k0yp = perm[i0 + yp];

    const float kc = perm[gid];
    const float sa = wsat[gid];
    // prior saturation: shifted wsat, or sini at t=0 (safe unconditional load)
    const float prload = wsat[gid - ((t > 0) ? TSTRIDE : 0)];

    const float pr = (t == 0) ? sini : prload;

    // mobility constants from siniuse
    const float S0 = (sini - 0.1f) * 1.25f;      // /(1-SWI-SWR)=0.8
    const float cw = S0 * S0;
    const float ct = cw + (1.0f - S0) * (1.0f - S0) * (1.0f / 2.75f);
    const float scale = 7.8125e-8f;              // dxf * 1e-5 = 1e-5/128
    const float DK = 32000.0f;                   // 500 (perm rescale) * 64 (0.5/h)

    const float uc   = pc  * 1000.0f;
    const float uxm2 = pxm * 1000.0f;
    const float uxp2 = pxp * 1000.0f;
    const float uym2 = pym * 1000.0f;
    const float uyp2 = pyp * 1000.0f;

    const float dudx   = (uxp2 - uxm2) * 64.0f;
    const float dudy   = (uyp2 - uym2) * 64.0f;
    const float dduddx = (uxp2 - 2.0f * uc + uxm2) * 16384.0f;
    const float dduddy = (uyp2 - 2.0f * uc + uym2) * 16384.0f;

    const float dpx = (k0xp - k0xm) * DK;
    const float dpy = (k0yp - k0ym) * DK;
    const float g1  = dpx * dudx + dpy * dudy;
    const float lap = dduddx + dduddy;

    const float a   = 500.0f * kc;
    const float dsw = fmaxf(sa - pr, 0.001f);
    const float S   = (pr - 0.1f) * 1.25f;
    const float Mw  = S * S;
    const float Mo  = (1.0f - S) * (1.0f - S) * (1.0f / 2.75f);
    const float a1  = (Mw + Mo) * a;
    const float a1w = Mw * a;

    const float pl = scale * (q * 5000.0f + ct * g1 + a1 * lap);
    const float flux = cw * g1 + a1w * lap;
    const float sl = scale * (ph * (dsw / (tm * 6000.0f)) - (flux + qw * 5000.0f));

    __builtin_nontemporal_store(pl, out + gid);
    __builtin_nontemporal_store(sl, out + gid + NTOT);
}

extern "C" void kernel_launch(void* const* d_in, const int* in_sizes, int n_in,
                              void* d_out, int out_size, void* d_ws, size_t ws_size,
                              hipStream_t stream) {
    const float* pressure = (const float*)d_in[0];
    const float* perm     = (const float*)d_in[1];
    const float* Q        = (const float*)d_in[2];
    const float* Qw       = (const float*)d_in[3];
    const float* Time_    = (const float*)d_in[4];
    // d_in[5] = Pini (unused by the reference)
    const float* Phi      = (const float*)d_in[6];
    const float* Swini    = (const float*)d_in[7];
    const float* wsat     = (const float*)d_in[8];
    float* out = (float*)d_out;

    const int threads = 256;
    blackoil_kernel<<<NBLOCKS, threads, 0, stream>>>(
        pressure, perm, Q, Qw, Time_, Phi, Swini, wsat, out);
}